// Round 11
// baseline (104.111 us; speedup 1.0000x reference)
//
#include <hip/hip_runtime.h>
#include <hip/hip_bf16.h>

typedef __bf16 bf16;
typedef __attribute__((ext_vector_type(8))) __bf16 bf16x8;
typedef __attribute__((ext_vector_type(4))) __bf16 bf16x4;
typedef __attribute__((ext_vector_type(4))) float f32x4;
typedef __attribute__((ext_vector_type(4))) int i32x4;
typedef __attribute__((ext_vector_type(2))) int i32x2;

#define CH 192
#define MAT (CH * CH)            // 36864
#define NF 145                   // canonical frequencies of 17x17 grid (conj symmetry)
#define NELEM (CH * CH * 9)      // 331776
#define XSCALE 9.765625e-4f      // 2^-10, exact; sigma = 1024*(s3/289)^(1/16)
#define W17 0.36959913571644626f // 2*pi/17

// ---------------------------------------------------------------------------
// sigma = ||G^3(K)||_F^(1/8) via 17x17 spectral sampling (exact Parseval).
// ROUND-16 CHANGE (break the 16-wave register bind): r10 showed VGPR=64 --
// at 16 waves the 128-reg/wave budget minus 72 accums leaves ~56 arch VGPRs,
// so B-frag reads can't batch and MFMAs stall on lgkmcnt (per-active-CU
// MfmaUtil ~26% vs 35% pipe floor). Restructure k_g3:
//  - 8 waves (512 thr), ONE 96x48 tile per wave (rb=(w>>2)*96, cb=(w&3)*48);
//    amdgpu_waves_per_eu(2,2) -> 256 regs/wave. Live: 144 acc + 48 A-frag
//    + 12 B + addr ~= 220 <= 256. A-frags reused over 3 nt -> LDS reads
//    864/round (-25%); MFMA burst per B-pair 12 -> 24 (dep dist 12).
//  - staging: 9 passes x 512 = 4608 chunks EXACT (no tail).
//  - round 3: skip the 2 fully-below-diag tiles (w=4,5); per-ELEMENT norm
//    weights (col>row: 2, col==row: 1, else 0) -- coverage of the upper
//    triangle is complete across computed tiles.
// BITWISE: every H entry keeps the identical 6-step MFMA chain and bf16
// conversion points; only wave->tile map + s3 reduction order change
// (absmax stayed 2.441e-4 across r8->r10 under the same kind of remap).
// Lessons pinned:
//  - 16-wave block = 128 regs/wave total => ~56 arch after accums => no
//    prefetch headroom. 8-wave + waves_per_eu(2,2) => 256. WATCH: if
//    VGPR_Count comes back <=128 / WRITE_SIZE balloons, allocator defied
//    the attr (r2/r3 ghost) -> revert.
//  - ci Hermitian mirror NOT bitwise (r9). cr is. No mirrors.
//  - Lane-adjacent addresses must be contiguous (r7 gather +22us).
//  - XOR chunk swizzle c'=(c&~7)|((c&7)^(r&7)) BOTH sides: conflicts 2M->0.
//  - FETCH ~9MB = Kt x8 XCDs; WRITE ~8MB = harness-fill dirty-L2 writeback,
//    NOT scratch. Don't chase them.
//  - harness ws fill (~44 us) is inside the timed window: floor = 44 + work.
// ws layout: [0] float s3; [256] Kt f32 [i][a][o] 9 planes (1.33 MB).
// ---------------------------------------------------------------------------

__device__ __forceinline__ int swz8(int c, int r) {
    return (c & ~7) | ((c & 7) ^ (r & 7));       // 16-B chunk XOR swizzle
}

// Kt[i*MAT + a*CH + o] = K[(o*CH+a)*9 + i]; coalesced 36-B read per thread,
// 9 scattered scalar writes (fire-and-forget). Also zeroes s3.
__global__ void k_tr(const float* __restrict__ K, float* __restrict__ Kt,
                     float* __restrict__ s3) {
    int p = blockIdx.x * 256 + threadIdx.x;      // 144 blocks = 36864 rows
    if (p == 0) *s3 = 0.0f;
    int o = p / CH, a = p % CH;
    const float* src = K + (size_t)p * 9;
#pragma unroll
    for (int i = 0; i < 9; ++i)
        Kt[(size_t)i * MAT + a * CH + o] = src[i];
}

// ---------------------------------------------------------------------------
// k_g3: per-frequency fused DFT + triple gram. One block = one freq, 512 thr.
// Staging: 9-plane coeff DFT, coalesced f32x4 plane reads -> swizzled LDS
// (Re/Im slabs [192][192] bf16, 147456 B). Rounds: 8 waves, wave w owns a
// 96x48 tile; MFMA mt-major (6 deep) -> barrier -> transposed-packed b64
// write-back -> barrier. Round 3: skip fully-below tiles; per-element-
// weighted Frobenius norm -> atomic.
// ---------------------------------------------------------------------------
__global__ __launch_bounds__(512, 2)
__attribute__((amdgpu_waves_per_eu(2, 2)))
void k_g3(const float* __restrict__ Kt, float* __restrict__ s3) {
    __shared__ __align__(16) bf16 lds[2 * MAT];   // 147456 B
    __shared__ float twc[17], tws[17];
    __shared__ float red[8];
    int f = blockIdx.x;                 // 145 blocks
    int tid = threadIdx.x;
    int lane = tid & 63, w = tid >> 6;
    int ml = lane & 15, kqc = lane >> 4;
    int mlb = ml & 7;                   // swizzle row-bit (bands are 0 mod 16)
    int rb = (w >> 2) * 96;             // 2 row bands (96 rows each)
    int cb = (w & 3) * 48;              // 4 col bands (48 cols each)
    // round 3: tiles fully below the diagonal contribute nothing
    bool comp3 = !(rb == 96 && cb < 96);   // skip waves 4,5

    if (tid < 17) {
        float s, c;
        __sincosf(-W17 * (float)tid, &s, &c);
        twc[tid] = c; tws[tid] = s;
    }
    __syncthreads();

    // ---- 9 block-uniform complex coeffs c[y*3+x] = py^y * px^x * 2^-10 ----
    int fy, fx;
    if (f < 9) { fy = 0; fx = f; }
    else { int uu = f - 9; fy = 1 + uu / 17; fx = uu % 17; }
    float pyr = twc[fy], pyi = tws[fy];
    float pxr = twc[fx], pxi = tws[fx];
    int fx2 = 2 * fx; if (fx2 >= 17) fx2 -= 17;
    int fy2 = 2 * fy; if (fy2 >= 17) fy2 -= 17;
    float px2r = twc[fx2], px2i = tws[fx2];
    float py2r = twc[fy2], py2i = tws[fy2];
    float cR[9], cI[9];
    cR[0] = 1.0f;  cI[0] = 0.0f;
    cR[1] = pxr;   cI[1] = pxi;
    cR[2] = px2r;  cI[2] = px2i;
    cR[3] = pyr;   cI[3] = pyi;
    cR[4] = pyr * pxr - pyi * pxi;    cI[4] = pyr * pxi + pyi * pxr;
    cR[5] = pyr * px2r - pyi * px2i;  cI[5] = pyr * px2i + pyi * px2r;
    cR[6] = py2r;  cI[6] = py2i;
    cR[7] = py2r * pxr - py2i * pxi;  cI[7] = py2r * pxi + py2i * pxr;
    cR[8] = py2r * px2r - py2i * px2i; cI[8] = py2r * px2i + py2i * px2r;
#pragma unroll
    for (int i = 0; i < 9; ++i) { cR[i] *= XSCALE; cI[i] *= XSCALE; }  // exact 2^-10

    // ---- stage: X_f = sum_i c_i * plane_i -> swizzled LDS (4608 chunks) ----
#pragma unroll 1
    for (int j = 0; j < 9; ++j) {                 // 9 x 512 = 4608 exact
        int cidx = j * 512 + tid;
        int a = cidx / 24, c = cidx % 24;
        const float* base = Kt + a * CH + c * 8;
        float xr0 = 0.f, xr1 = 0.f, xr2 = 0.f, xr3 = 0.f;
        float xr4 = 0.f, xr5 = 0.f, xr6 = 0.f, xr7 = 0.f;
        float xi0 = 0.f, xi1 = 0.f, xi2 = 0.f, xi3 = 0.f;
        float xi4 = 0.f, xi5 = 0.f, xi6 = 0.f, xi7 = 0.f;
#pragma unroll
        for (int i = 0; i < 9; ++i) {
            f32x4 lo = *(const f32x4*)(base + (size_t)i * MAT);
            f32x4 hi = *(const f32x4*)(base + (size_t)i * MAT + 4);
            float r = cR[i], m = cI[i];
            xr0 += r * lo[0]; xi0 += m * lo[0];
            xr1 += r * lo[1]; xi1 += m * lo[1];
            xr2 += r * lo[2]; xi2 += m * lo[2];
            xr3 += r * lo[3]; xi3 += m * lo[3];
            xr4 += r * hi[0]; xi4 += m * hi[0];
            xr5 += r * hi[1]; xi5 += m * hi[1];
            xr6 += r * hi[2]; xi6 += m * hi[2];
            xr7 += r * hi[3]; xi7 += m * hi[3];
        }
        bf16x8 vr, vi;
        vr[0] = (bf16)xr0; vr[1] = (bf16)xr1; vr[2] = (bf16)xr2; vr[3] = (bf16)xr3;
        vr[4] = (bf16)xr4; vr[5] = (bf16)xr5; vr[6] = (bf16)xr6; vr[7] = (bf16)xr7;
        vi[0] = (bf16)xi0; vi[1] = (bf16)xi1; vi[2] = (bf16)xi2; vi[3] = (bf16)xi3;
        vi[4] = (bf16)xi4; vi[5] = (bf16)xi5; vi[6] = (bf16)xi6; vi[7] = (bf16)xi7;
        int e = a * CH + swz8(c, a) * 8;          // swizzled (write side)
        *(i32x4*)&lds[e]       = __builtin_bit_cast(i32x4, vr);
        *(i32x4*)&lds[MAT + e] = __builtin_bit_cast(i32x4, vi);
    }
    __syncthreads();

    // per-thread frag row constants
    int arow[6], brow[3];
#pragma unroll
    for (int i = 0; i < 6; ++i) arow[i] = (rb + i * 16 + ml) * CH;
#pragma unroll
    for (int i = 0; i < 3; ++i) brow[i] = (cb + i * 16 + ml) * CH;

    f32x4 cr[6][3], ci[6][3];
#pragma unroll 1
    for (int round = 0; round < 3; ++round) {
        bool active = (round < 2) || comp3;
#pragma unroll
        for (int i = 0; i < 6; ++i)
#pragma unroll
            for (int j = 0; j < 3; ++j) {
                cr[i][j] = f32x4{0.f, 0.f, 0.f, 0.f};
                ci[i][j] = f32x4{0.f, 0.f, 0.f, 0.f};
            }
        if (active) {
#pragma unroll
            for (int ks8 = 0; ks8 < 24; ks8 += 4) {     // K step 32 = 4 chunks
                int sw = swz8(ks8 + kqc, mlb) * 8;
                bf16x8 ar[6], ai[6];
#pragma unroll
                for (int mt = 0; mt < 6; ++mt) {
                    int e = arow[mt] + sw;
                    ar[mt] = *(const bf16x8*)&lds[e];
                    ai[mt] = *(const bf16x8*)&lds[MAT + e];
                }
#pragma unroll
                for (int nt = 0; nt < 3; ++nt) {
                    int e = brow[nt] + sw;
                    bf16x8 br = *(const bf16x8*)&lds[e];
                    bf16x8 bi = *(const bf16x8*)&lds[MAT + e];
                    i32x4 u = __builtin_bit_cast(i32x4, br);
                    u ^= 0x80008000;                    // nbr = -br (8 bf16)
                    bf16x8 nbr = __builtin_bit_cast(bf16x8, u);
                    // mt-major, 6 deep: per-accumulator order identical to
                    // r10 (+ar*br, +ai*bi | +ar*bi, +ai*nbr) -> bitwise id
                    __builtin_amdgcn_s_setprio(1);
#pragma unroll
                    for (int mt = 0; mt < 6; ++mt)
                        cr[mt][nt] = __builtin_amdgcn_mfma_f32_16x16x32_bf16(ar[mt], br,  cr[mt][nt], 0, 0, 0);
#pragma unroll
                    for (int mt = 0; mt < 6; ++mt)
                        ci[mt][nt] = __builtin_amdgcn_mfma_f32_16x16x32_bf16(ar[mt], bi,  ci[mt][nt], 0, 0, 0);
#pragma unroll
                    for (int mt = 0; mt < 6; ++mt)
                        cr[mt][nt] = __builtin_amdgcn_mfma_f32_16x16x32_bf16(ai[mt], bi,  cr[mt][nt], 0, 0, 0);
#pragma unroll
                    for (int mt = 0; mt < 6; ++mt)
                        ci[mt][nt] = __builtin_amdgcn_mfma_f32_16x16x32_bf16(ai[mt], nbr, ci[mt][nt], 0, 0, 0);
                    __builtin_amdgcn_s_setprio(0);
                }
            }
        }
        if (round < 2) {
            __syncthreads();                        // all LDS reads done
            // transposed-packed write-back: store H^T (bitwise-Hermitian ->
            // transposes cancel across rounds). Lane's 4 rr rows are 4
            // consecutive elems of the stored column -> one b64 per plane.
            int lrq = kqc * 4;
#pragma unroll
            for (int mt = 0; mt < 6; ++mt) {
                int row0 = rb + mt * 16 + lrq;      // multiple of 4
                int rc = row0 >> 3, rlo = row0 & 7; // rlo in {0,4}
#pragma unroll
                for (int nt = 0; nt < 3; ++nt) {
                    int col = cb + nt * 16 + ml;
                    int e = col * CH + swz8(rc, mlb) * 8 + rlo;  // col&7 == mlb
                    bf16x4 pr, pi;
#pragma unroll
                    for (int rr = 0; rr < 4; ++rr) {
                        pr[rr] = (bf16)cr[mt][nt][rr];
                        pi[rr] = (bf16)ci[mt][nt][rr];
                    }
                    *(i32x2*)&lds[e]       = __builtin_bit_cast(i32x2, pr);
                    *(i32x2*)&lds[MAT + e] = __builtin_bit_cast(i32x2, pi);
                }
            }
            __syncthreads();                        // writes visible to round+1
        }
    }

    // ---- norm of round-3 accums: per-element weight 2/1/0 (above/diag/
    // below); computed tiles cover the upper triangle exactly once ----
    float loc = 0.f;
#pragma unroll
    for (int mt = 0; mt < 6; ++mt)
#pragma unroll
        for (int nt = 0; nt < 3; ++nt)
#pragma unroll
            for (int rr = 0; rr < 4; ++rr) {
                int row = rb + mt * 16 + kqc * 4 + rr;
                int col = cb + nt * 16 + ml;
                float wt = (col > row) ? 2.0f : ((col == row) ? 1.0f : 0.0f);
                loc += wt * (cr[mt][nt][rr] * cr[mt][nt][rr] +
                             ci[mt][nt][rr] * ci[mt][nt][rr]);
            }
#pragma unroll
    for (int off = 32; off > 0; off >>= 1) loc += __shfl_down(loc, off, 64);
    if (lane == 0) red[w] = loc;
    __syncthreads();
    if (tid == 0) {
        float base = (f == 0) ? 1.0f : 2.0f;        // conj-pair weight over freqs
        float acc = 0.f;
#pragma unroll
        for (int i = 0; i < 8; ++i) acc += red[i];
        atomicAdd(s3, base * acc);
    }
}

// sigma = 1024 * (s3/289)^(1/16);  out = K / sigma
__global__ void k_scale(const float* __restrict__ K, float* __restrict__ out,
                        const float* __restrict__ s3) {
    float sig = 1024.0f * exp2f(log2f((*s3) * (1.0f / 289.0f)) * 0.0625f);
    float inv = 1.0f / sig;
    int i = (blockIdx.x * 256 + threadIdx.x) * 4;   // 324 blocks exact
    f32x4 v = *(const f32x4*)(K + i);
    v *= inv;
    *(f32x4*)(out + i) = v;
}

extern "C" void kernel_launch(void* const* d_in, const int* in_sizes, int n_in,
                              void* d_out, int out_size, void* d_ws, size_t ws_size,
                              hipStream_t stream) {
    const float* K = (const float*)d_in[0];
    float* out = (float*)d_out;
    char* ws = (char*)d_ws;
    float* s3 = (float*)ws;
    float* Kt = (float*)(ws + 256);

    k_tr<<<NELEM / (256 * 9), 256, 0, stream>>>(K, Kt, s3);   // 9-plane Kt + s3=0
    k_g3<<<NF, 512, 0, stream>>>(Kt, s3);                     // DFT + 3 gram rounds
    k_scale<<<NELEM / 1024, 256, 0, stream>>>(K, out, s3);    // out = K/sigma
}